// Round 3
// baseline (720.086 us; speedup 1.0000x reference)
//
#include <hip/hip_runtime.h>

#define T_STEPS 1024
#define LOG2E 1.44269504088896340736f
// H = F = 6; 24 gate rows, PyTorch order: i[0:6) f[6:12) g[12:18) o[18:24)
//
// Mapping: quad (4 lanes) = (element, hidden unit j). Lane g = hl&3 holds gate
// g of unit j = hl>>2. Element = 32-lane half-wave (quads 0..5 active, 6..7
// ballast). 2 elements/wave -> 4096 elem = 2048 waves = 2 waves/SIMD.
// Gate exchange i,f,g,o within the quad = DPP quad_perm broadcasts (VALU pipe,
// no DS round trip). Only cross-quad op: h broadcast via ds_bpermute (6 per
// layer, both layers' 12 issued together -> ~1 LGKM round trip per iter).

__device__ __forceinline__ float vexp2(float x){ return __builtin_amdgcn_exp2f(x); }
__device__ __forceinline__ float vrcp (float x){ return __builtin_amdgcn_rcpf(x); }
__device__ __forceinline__ float bperm(int a4, float v){
    return __int_as_float(__builtin_amdgcn_ds_bpermute(a4, __float_as_int(v)));
}
template<int CTRL>
__device__ __forceinline__ float qb(float v){   // broadcast one quad lane to all 4
    return __int_as_float(__builtin_amdgcn_update_dpp(
        0, __float_as_int(v), CTRL, 0xF, 0xF, true));
}

__global__ __launch_bounds__(256) void lstm2_kernel(
    const float* __restrict__ x,
    const float* __restrict__ wih0, const float* __restrict__ whh0,
    const float* __restrict__ bih0, const float* __restrict__ bhh0,
    const float* __restrict__ wih1, const float* __restrict__ whh1,
    const float* __restrict__ bih1, const float* __restrict__ bhh1,
    float* __restrict__ out, int Btot)
{
    const int tid  = threadIdx.x;
    const int lane = tid & 63;
    const int hl   = lane & 31;          // lane within element
    const int eb   = lane & 32;          // element base lane in wave
    const int g    = hl & 3;             // 0:i 1:f 2:g 3:o
    int j = hl >> 2; if (j > 5) j -= 6;  // ballast quads alias units 0,1 (unused)
    const int r = g * 6 + j;             // gate row

    int b = blockIdx.x * 8 + (tid >> 5); // 8 elements per 256-thread block
    const bool valid = (b < Btot);
    if (!valid) b = Btot - 1;            // clamp; stores predicated off

    // activation constants: sigma(x)=rcp(1+exp2(-x*log2e)); tanh folds 2x into scale
    const float kscale = (g == 2) ? (-2.0f * LOG2E) : (-LOG2E);
    const float mulc   = (g == 2) ? 2.0f : 1.0f;
    const float addc   = (g == 2) ? -1.0f : 0.0f;

    // per-lane weight rows
    float wih0v[6], whh0v[6], wih1v[6], whh1v[6];
#pragma unroll
    for (int k = 0; k < 6; ++k) {
        wih0v[k] = wih0[r * 6 + k]; whh0v[k] = whh0[r * 6 + k];
        wih1v[k] = wih1[r * 6 + k]; whh1v[k] = whh1[r * 6 + k];
    }
    const float b0 = bih0[r] + bhh0[r];
    const float b1 = bih1[r] + bhh1[r];

    // h-broadcast source lanes: gate-i lane of quad k within this element
    int ba[6];
#pragma unroll
    for (int k = 0; k < 6; ++k) ba[k] = (eb + 4 * k) * 4;

    const float* px   = x   + (size_t)b * (T_STEPS * 6);
    float*       pout = out + (size_t)b * (T_STEPS * 6);

    auto loadx = [&](int t, float v[6]) {
        const float2* p2 = reinterpret_cast<const float2*>(px + (size_t)t * 6);
        float2 a = p2[0], bq = p2[1], cq = p2[2];
        v[0] = a.x; v[1] = a.y; v[2] = bq.x; v[3] = bq.y; v[4] = cq.x; v[5] = cq.y;
    };
    auto dotW = [&](const float w[6], const float in[6], float bias) -> float {
        float e0 = fmaf(w[0], in[0], bias);
        e0 = fmaf(w[2], in[2], e0);
        e0 = fmaf(w[4], in[4], e0);
        float e1 = w[1] * in[1];
        e1 = fmaf(w[3], in[3], e1);
        e1 = fmaf(w[5], in[5], e1);
        return e0 + e1;
    };
    auto act = [&](float gp) -> float {
        return fmaf(mulc, vrcp(1.0f + vexp2(gp * kscale)), addc);
    };
    auto tanhc = [&](float c) -> float {
        return fmaf(2.0f, vrcp(1.0f + vexp2(c * (-2.0f * LOG2E))), -1.0f);
    };
    // quad gate exchange + cell update; returns h (valid on all quad lanes)
    auto cell = [&](float a, float& c) -> float {
        float ai = qb<0x00>(a);
        float af = qb<0x55>(a);
        float ag = qb<0xAA>(a);
        float ao = qb<0xFF>(a);
        c = fmaf(af, c, ai * ag);
        return ao * tanhc(c);
    };

    float h0s[6], h1s[6];
#pragma unroll
    for (int k = 0; k < 6; ++k) { h0s[k] = 0.0f; h1s[k] = 0.0f; }
    float c0 = 0.0f, c1 = 0.0f;

    // ---- prologue: layer0 @ t=0 (h=c=0) ----
    float xv[6];
    loadx(0, xv);
    float a0 = act(dotW(wih0v, xv, b0));
    float h0v = cell(a0, c0);
#pragma unroll
    for (int k = 0; k < 6; ++k) h0s[k] = bperm(ba[k], h0v);

    float xn[6];
    loadx(1, xn);
    float xacc0 = dotW(wih0v, xn, b0);     // layer0 input-part @ t=1
    float xacc1 = dotW(wih1v, h0s, b1);    // layer1 input-part @ t=0
    loadx(2, xn);                           // xn = x(2)

    // ---- body: iter t = layer1(t-1) + layer0(t), independent chains ----
    for (int t = 1; t < T_STEPS; ++t) {
        float pre1 = dotW(whh1v, h1s, xacc1);
        float pre0 = dotW(whh0v, h0s, xacc0);
        float a1 = act(pre1);
        float a0b = act(pre0);
        float h1v = cell(a1, c1);
        h0v = cell(a0b, c0);
        // both layers' broadcasts in flight together -> one LGKM wait
#pragma unroll
        for (int k = 0; k < 6; ++k) h1s[k] = bperm(ba[k], h1v);
#pragma unroll
        for (int k = 0; k < 6; ++k) h0s[k] = bperm(ba[k], h0v);
        // off-critical-path work while DS is in flight
        xacc0 = dotW(wih0v, xn, b0);        // uses x(t+1)
        int tn = t + 2; if (tn > T_STEPS - 1) tn = T_STEPS - 1;
        loadx(tn, xn);                      // prefetch x(t+2)
        if (valid && hl < 24 && g == 0)
            pout[(size_t)(t - 1) * 6 + j] = h1v;
        xacc1 = dotW(wih1v, h0s, b1);       // needs fresh h0s (after wait)
    }

    // ---- epilogue: layer1 @ t = T-1 ----
    {
        float a1 = act(dotW(whh1v, h1s, xacc1));
        float h1v = cell(a1, c1);
        if (valid && hl < 24 && g == 0)
            pout[(size_t)(T_STEPS - 1) * 6 + j] = h1v;
    }
}

extern "C" void kernel_launch(void* const* d_in, const int* in_sizes, int n_in,
                              void* d_out, int out_size, void* d_ws, size_t ws_size,
                              hipStream_t stream)
{
    const float* x    = (const float*)d_in[0];
    const float* wih0 = (const float*)d_in[1];
    const float* whh0 = (const float*)d_in[2];
    const float* bih0 = (const float*)d_in[3];
    const float* bhh0 = (const float*)d_in[4];
    const float* wih1 = (const float*)d_in[5];
    const float* whh1 = (const float*)d_in[6];
    const float* bih1 = (const float*)d_in[7];
    const float* bhh1 = (const float*)d_in[8];
    float* out = (float*)d_out;

    const int Btot   = in_sizes[0] / (T_STEPS * 6);
    const int blocks = (Btot + 7) / 8;     // 8 elements per 256-thread block
    hipLaunchKernelGGL(lstm2_kernel, dim3(blocks), dim3(256), 0, stream,
                       x, wih0, whh0, bih0, bhh0, wih1, whh1, bih1, bhh1, out, Btot);
}